// Round 2
// baseline (1004.005 us; speedup 1.0000x reference)
//
#include <hip/hip_runtime.h>

typedef unsigned short u16;
typedef unsigned int   u32;
typedef __attribute__((ext_vector_type(4))) float f32x4;
typedef __attribute__((ext_vector_type(8))) short short8;

#define DI static __device__ __forceinline__

// ---- bf16 split helpers (round-to-nearest-even) ----
DI u16 f2bf(float x){ union{float f;u32 u;}v; v.f=x; u32 r=v.u + 0x7fffu + ((v.u>>16)&1u); return (u16)(r>>16); }
DI float bf2f(u16 h){ union{u32 u;float f;}v; v.u=((u32)h)<<16; return v.f; }

DI void gl_lds16(const u16* g, u16* l){
  __builtin_amdgcn_global_load_lds((const __attribute__((address_space(1))) void*)g,
                                   (__attribute__((address_space(3))) void*)l, 16, 0, 0);
}

// ===================== prep kernels =====================

// bn buf layout: which*2176 floats: [0..1088)=scale, [1088..2176)=shift
__global__ void k_bnprep(const float* __restrict__ bnE, const float* __restrict__ bn1,
                         const float* __restrict__ bn2, const float* __restrict__ bnA,
                         const float* __restrict__ bnT, float* __restrict__ out){
  int i = blockIdx.x*256 + threadIdx.x;
  if(i >= 5*1088) return;
  int w = i/1088, c = i - w*1088;
  const float* b = (w==0)?bnE:(w==1)?bn1:(w==2)?bn2:(w==3)?bnA:bnT;
  float g=b[c], be=b[1088+c], mu=b[2176+c], va=b[3264+c];
  float s = g / sqrtf(va + 1e-5f);
  out[w*2176 + c] = s;
  out[w*2176 + 1088 + c] = be - mu*s;
}

__global__ void k_zero(float* p, int n){ int i = blockIdx.x*256+threadIdx.x; if(i<n) p[i]=0.f; }

// x (B,T,17,32,4) -> fmat f32 [4096,544] (m=bt*4+n, c=j*32+cp) + split
__global__ void k_pack_f(const float* __restrict__ x, float* __restrict__ fmat,
                         u16* __restrict__ fhi, u16* __restrict__ flo){
  int bt = blockIdx.x;
  const float* xr = x + (size_t)bt*2176;
  for(int t=threadIdx.x; t<2176; t+=256){
    int c = t>>2, n = t&3;
    float v = xr[t];
    size_t o = (size_t)(bt*4+n)*544 + c;
    fmat[o] = v;
    u16 h = f2bf(v); fhi[o]=h; flo[o]=f2bf(v - bf2f(h));
  }
}

// generic weight pack: dst[o,k] (o<Opad=gridDim.y) = src piecewise, zero-padded rows
__global__ void k_pack_w(const float* __restrict__ src, int off1, int off2, int O1,
                         int rs, int cs, int O, int K,
                         u16* __restrict__ dhi, u16* __restrict__ dlo){
  int o = blockIdx.y;
  int k = blockIdx.x*256 + threadIdx.x;
  if(k >= K) return;
  float v = 0.f;
  if(o < O){
    size_t idx = (o<O1) ? (size_t)off1 + (size_t)o*rs + (size_t)k*cs
                        : (size_t)off2 + (size_t)(o-O1)*rs + (size_t)k*cs;
    v = src[idx];
  }
  size_t d = (size_t)o*K + k;
  u16 h=f2bf(v); dhi[d]=h; dlo[d]=f2bf(v - bf2f(h));
}

// q[m,o] = sum_k p[m,k]*w_pos[o,k], p from pos_2d directly. block per m.
__global__ void k_q(const float* __restrict__ pos, const float* __restrict__ w_pos,
                    float* __restrict__ q){
  int m = blockIdx.x; int bt = m>>2, n = m&3;
  __shared__ float pr[34];
  if(threadIdx.x<34){ int j = threadIdx.x>>1, d = threadIdx.x&1;
    pr[threadIdx.x] = pos[(size_t)bt*136 + j*8 + d*4 + n]; }
  __syncthreads();
  for(int o=threadIdx.x;o<1088;o+=256){
    const float* wr = w_pos + (size_t)o*34;
    float s = 0.f;
    #pragma unroll
    for(int k=0;k<34;k++) s += pr[k]*wr[k];
    q[(size_t)m*1088 + o] = s;
  }
}

// h0[bt,i,j,o] = relu(sE*(u_i+v_j)+tE) + q_i - q_j + b_pos ; split-store
// one block per bt; u,v,q rows staged in LDS (cuts HBM re-reads 4x -> 1x)
__global__ void k_expand(const float* __restrict__ uv, const float* __restrict__ q,
                         const float* __restrict__ bn, const float* __restrict__ b_pos,
                         u16* __restrict__ hh, u16* __restrict__ hl){
  __shared__ float su[4][1088], sv[4][1088], sq[4][1088];
  int bt = blockIdx.x;
  for(int t=threadIdx.x; t<4*1088; t+=256){
    int r = t/1088, o = t - r*1088;
    su[r][o] = uv[(size_t)(bt*4+r)*2176 + o];
    sv[r][o] = uv[(size_t)(bt*4+r)*2176 + 1088 + o];
    sq[r][o] = q[(size_t)(bt*4+r)*1088 + o];
  }
  __syncthreads();
  for(int t=threadIdx.x; t<16*1088; t+=256){
    int ij = t/1088, o = t - ij*1088; int i = ij>>2, j = ij&3;
    float xv = bn[o]*(su[i][o]+sv[j][o]) + bn[1088+o];
    xv = fmaxf(xv,0.f) + sq[i][o]-sq[j][o]+b_pos[o];
    size_t idx = (size_t)(bt*16+ij)*1088 + o;
    u16 h=f2bf(xv); hh[idx]=h; hl[idx]=f2bf(xv-bf2f(h));
  }
}

// ===================== split-bf16 MFMA GEMM =====================
// C[M,Npad] = A[M,K] @ B[Npad,K]^T with A,B given as bf16 hi/lo pairs.
// 128x128 tile, BK=32, 4 waves (2x2) of 64x64, mfma 16x16x32_bf16 x3 (hh, lh, hl).
// LDS 16B-slot swizzle: LDS slot p of row r holds logical k-slot p ^ ((r>>1)&3).
// Staged via global_load_lds (linear LDS dest) with pre-swizzled per-lane global
// source; ds_read applies the same involution -> 2 lanes/bank-group (free floor).
// EPI: 0 = f32 store    (out_f, ldo, col<Nout)
//      1 = bn+relu -> split store (out_hi/lo)
//      2 = bn+relu + residual(res_hi/lo) -> split store
//      3 = +bias[col] -> f32 store
//      4 = bn+relu * wred[col], reduce over cols -> atomicAdd red_out[row]
template<int EPI>
__global__ __launch_bounds__(256,2)
void k_gemm(const u16* __restrict__ Ahi, const u16* __restrict__ Alo,
            const u16* __restrict__ Bhi, const u16* __restrict__ Blo,
            int K, int Nout, int ldo,
            float* __restrict__ out_f, u16* __restrict__ out_hi, u16* __restrict__ out_lo,
            const float* __restrict__ sv, const float* __restrict__ tv,
            const u16* __restrict__ res_hi, const u16* __restrict__ res_lo,
            const float* __restrict__ bias,
            const float* __restrict__ wred, float* __restrict__ red_out)
{
  __shared__ u16 Ah[2][4096], Al[2][4096], Bh[2][4096], Bl[2][4096];
  __shared__ float red[128];
  const int tid = threadIdx.x, lane = tid&63, wave = tid>>6;
  const int wm = wave>>1, wn = wave&1;
  const int m0 = blockIdx.x*128, n0 = blockIdx.y*128;
  if(EPI==4 && tid<128) red[tid]=0.f;

  auto stage = [&](int buf, int kt){
    const int k0 = kt*32;
    #pragma unroll
    for(int c=0;c<2;c++){
      int s   = (wave*2+c)*64 + lane;      // 16B slot index 0..511
      int row = s>>2;
      int kg  = (s&3) ^ ((row>>1)&3);      // inverse swizzle on global side
      size_t ga = (size_t)(m0+row)*K + k0 + kg*8;
      size_t gb = (size_t)(n0+row)*K + k0 + kg*8;
      int lo = (wave*2+c)*512;             // u16 offset (wave-uniform)
      gl_lds16(Ahi+ga, &Ah[buf][lo]);
      gl_lds16(Alo+ga, &Al[buf][lo]);
      gl_lds16(Bhi+gb, &Bh[buf][lo]);
      gl_lds16(Blo+gb, &Bl[buf][lo]);
    }
  };

  f32x4 acc[4][4];
  #pragma unroll
  for(int i=0;i<4;i++)
    #pragma unroll
    for(int j=0;j<4;j++){ acc[i][j][0]=0.f; acc[i][j][1]=0.f; acc[i][j][2]=0.f; acc[i][j][3]=0.f; }

  const int NT = K>>5;
  stage(0,0);
  __syncthreads();                          // drains vmcnt before reads
  int buf = 0;
  // read-side swizzle: logical slot q=lane>>4 of row (..+lane&15) sits at
  // LDS slot q ^ ((row>>1)&3); row>>1 bits from lane&15 only (base mult of 16).
  const int swz = ((lane>>4) ^ (((lane&15)>>1)&3))<<3;   // u16 offset in row
  const int iA = ((wm*64 + (lane&15))<<5) + swz;
  const int iB = ((wn*64 + (lane&15))<<5) + swz;

  for(int kt=0; kt<NT; ++kt){
    if(kt+1<NT) stage(buf^1, kt+1);
    short8 ah[4],al[4],bh[4],bl[4];
    #pragma unroll
    for(int i=0;i<4;i++){
      ah[i] = *(const short8*)&Ah[buf][iA + i*512];
      al[i] = *(const short8*)&Al[buf][iA + i*512];
      bh[i] = *(const short8*)&Bh[buf][iB + i*512];
      bl[i] = *(const short8*)&Bl[buf][iB + i*512];
    }
    #pragma unroll
    for(int mi=0;mi<4;mi++)
      #pragma unroll
      for(int ni=0;ni<4;ni++){
        acc[mi][ni] = __builtin_amdgcn_mfma_f32_16x16x32_bf16(ah[mi],bh[ni],acc[mi][ni],0,0,0);
        acc[mi][ni] = __builtin_amdgcn_mfma_f32_16x16x32_bf16(al[mi],bh[ni],acc[mi][ni],0,0,0);
        acc[mi][ni] = __builtin_amdgcn_mfma_f32_16x16x32_bf16(ah[mi],bl[ni],acc[mi][ni],0,0,0);
      }
    __syncthreads();                        // all reads done + next stage landed
    buf ^= 1;
  }

  const int r0 = m0 + wm*64 + ((lane>>4)<<2);
  const int c0 = n0 + wn*64 + (lane&15);

  if constexpr (EPI==0){
    #pragma unroll
    for(int mi=0;mi<4;mi++)
      #pragma unroll
      for(int ni=0;ni<4;ni++){
        int col = c0 + ni*16;
        if(col < Nout){
          #pragma unroll
          for(int r=0;r<4;r++)
            out_f[(size_t)(r0+mi*16+r)*ldo + col] = acc[mi][ni][r];
        }
      }
  } else if constexpr (EPI==1 || EPI==2){
    #pragma unroll
    for(int mi=0;mi<4;mi++)
      #pragma unroll
      for(int ni=0;ni<4;ni++){
        int col = c0 + ni*16;
        if(col < Nout){
          float sc = sv[col], tc = tv[col];
          #pragma unroll
          for(int r=0;r<4;r++){
            float y = fmaxf(acc[mi][ni][r]*sc + tc, 0.f);
            size_t idx = (size_t)(r0+mi*16+r)*ldo + col;
            if(EPI==2) y += bf2f(res_hi[idx]) + bf2f(res_lo[idx]);
            u16 h = f2bf(y); out_hi[idx]=h; out_lo[idx]=f2bf(y - bf2f(h));
          }
        }
      }
  } else if constexpr (EPI==3){
    #pragma unroll
    for(int mi=0;mi<4;mi++)
      #pragma unroll
      for(int ni=0;ni<4;ni++){
        int col = c0 + ni*16;
        if(col < Nout){
          float bc = bias[col];
          #pragma unroll
          for(int r=0;r<4;r++)
            out_f[(size_t)(r0+mi*16+r)*ldo + col] = acc[mi][ni][r] + bc;
        }
      }
  } else { // EPI==4
    float rs4[4][4];
    #pragma unroll
    for(int mi=0;mi<4;mi++)
      #pragma unroll
      for(int r=0;r<4;r++) rs4[mi][r]=0.f;
    #pragma unroll
    for(int mi=0;mi<4;mi++)
      #pragma unroll
      for(int ni=0;ni<4;ni++){
        int col = c0 + ni*16;
        if(col < Nout){
          float sc = sv[col], tc = tv[col], wc = wred[col];
          #pragma unroll
          for(int r=0;r<4;r++)
            rs4[mi][r] += fmaxf(acc[mi][ni][r]*sc + tc, 0.f)*wc;
        }
      }
    #pragma unroll
    for(int off=1; off<16; off<<=1)
      #pragma unroll
      for(int mi=0;mi<4;mi++)
        #pragma unroll
        for(int r=0;r<4;r++)
          rs4[mi][r] += __shfl_xor(rs4[mi][r], off, 64);
    if((lane&15)==0){
      #pragma unroll
      for(int mi=0;mi<4;mi++)
        #pragma unroll
        for(int r=0;r<4;r++)
          atomicAdd(&red[wm*64 + mi*16 + ((lane>>4)<<2) + r], rs4[mi][r]);
    }
    __syncthreads();
    if(tid<128) atomicAdd(&red_out[m0+tid], red[tid]);
  }
}

// ===================== final fuse =====================
// block per bt: softmax over j of logits[bt,i,j]; fuse + f; coalesced float4 store
__global__ void k_fuse(const float* __restrict__ logits, const float* __restrict__ ag,
                       const float* __restrict__ fsft, const float* __restrict__ fmat,
                       float* __restrict__ out){
  int bt = blockIdx.x;
  float a[4][4];
  #pragma unroll
  for(int i=0;i<4;i++){
    float l0=logits[bt*16+i*4+0], l1=logits[bt*16+i*4+1],
          l2=logits[bt*16+i*4+2], l3=logits[bt*16+i*4+3];
    float mx = fmaxf(fmaxf(l0,l1),fmaxf(l2,l3));
    float e0=__expf(l0-mx), e1=__expf(l1-mx), e2=__expf(l2-mx), e3=__expf(l3-mx);
    float inv = 1.f/(e0+e1+e2+e3);
    a[i][0]=e0*inv; a[i][1]=e1*inv; a[i][2]=e2*inv; a[i][3]=e3*inv;
  }
  for(int d=threadIdx.x; d<544; d+=256){
    float fsv[4], ftv[4], fv[4];
    #pragma unroll
    for(int j=0;j<4;j++){
      fsv[j] = fsft[(size_t)(bt*4+j)*1088 + d];
      ftv[j] = fsft[(size_t)(bt*4+j)*1088 + 544 + d];
      fv[j]  = fmat[(size_t)(bt*4+j)*544 + d];
    }
    float o4[4];
    #pragma unroll
    for(int i=0;i<4;i++){
      float s = fv[i];
      #pragma unroll
      for(int j=0;j<4;j++){
        float fc = (j==i) ? fsv[j] : ftv[j]*ag[(size_t)(bt*16+i*4+j)*544 + d];
        s += a[i][j]*fc;
      }
      o4[i]=s;
    }
    *(float4*)(out + ((size_t)bt*544 + d)*4) = make_float4(o4[0],o4[1],o4[2],o4[3]);
  }
}

// ===================== launch =====================
extern "C" void kernel_launch(void* const* d_in, const int* in_sizes, int n_in,
                              void* d_out, int out_size, void* d_ws, size_t ws_size,
                              hipStream_t stream){
  (void)in_sizes; (void)n_in; (void)out_size; (void)ws_size;
  const float* x      = (const float*)d_in[0];
  const float* pos2d  = (const float*)d_in[1];
  const float* w_pos  = (const float*)d_in[2];
  const float* b_pos  = (const float*)d_in[3];
  const float* w_exp  = (const float*)d_in[4];
  const float* bnE    = (const float*)d_in[5];
  const float* w1     = (const float*)d_in[6];
  const float* bn1    = (const float*)d_in[7];
  const float* w2     = (const float*)d_in[8];
  const float* bn2    = (const float*)d_in[9];
  const float* w_ag   = (const float*)d_in[10];
  const float* bnA    = (const float*)d_in[11];
  const float* w_ag_s = (const float*)d_in[12];
  const float* b_ag_s = (const float*)d_in[13];
  const float* w_att  = (const float*)d_in[14];
  const float* bnT    = (const float*)d_in[15];
  const float* w_att_s= (const float*)d_in[16];
  // d_in[17] = b_att_s: scalar shift of softmax logits -> exactly cancels; unused.
  const float* Wm     = (const float*)d_in[18];
  float* out = (float*)d_out;

  char* ws = (char*)d_ws;
  size_t off = 0;
  auto alloc = [&](size_t b)->char*{ char* p = ws+off; off += (b+255)&~(size_t)255; return p; };

  float* fmat  = (float*)alloc(8912896);           // [4096,544] f32
  u16*   fhi   = (u16*)  alloc(4456448);
  u16*   flo   = (u16*)  alloc(4456448);
  float* bnbuf = (float*)alloc(43520);             // 5 x (scale[1088], shift[1088])
  u16*   wuv   = (u16*)  alloc(5013504);           // [2304,544] hi, lo at +2304*544
  u16*   w1p   = (u16*)  alloc(5013504);           // [1152,1088]
  u16*   w2p   = (u16*)  alloc(5013504);
  u16*   wagp  = (u16*)  alloc(5013504);
  u16*   watp  = (u16*)  alloc(5013504);
  u16*   wagsp = (u16*)  alloc(2785280);           // [640,1088]
  u16*   wWp   = (u16*)  alloc(2506752);           // [1152,544]
  float* logits= (float*)alloc(65536);             // [16384]
  char*  X0    = alloc(71303168);                  // h0 -> a1
  char*  X1    = alloc(71303168);                  // q -> r1 -> (ag | fsft)
  char*  X2    = alloc(71303168);                  // uv -> h2

  u16* h0h=(u16*)X0;            u16* h0l=(u16*)(X0+35651584);
  u16* a1h=(u16*)X0;            u16* a1l=(u16*)(X0+35651584);
  float* qb =(float*)X1;
  u16* r1h=(u16*)X1;            u16* r1l=(u16*)(X1+35651584);
  float* agb =(float*)X1;       float* fsft=(float*)(X1+35651584);
  float* uvb =(float*)X2;
  u16* h2h=(u16*)X2;            u16* h2l=(u16*)(X2+35651584);

  // ---- prep ----
  k_bnprep<<<22,256,0,stream>>>(bnE,bn1,bn2,bnA,bnT,bnbuf);
  k_zero  <<<64,256,0,stream>>>(logits,16384);
  k_pack_f<<<1024,256,0,stream>>>(x, fmat, fhi, flo);
  // [Wl | Wr] stacked: rows<1088 = w_exp[:, :544], rows>=1088 = w_exp[:, 544:]
  k_pack_w<<<dim3(3,2304),256,0,stream>>>(w_exp, 0,544,1088, 1088,1, 2176,544, wuv, wuv+2304*544);
  k_pack_w<<<dim3(5,1152),256,0,stream>>>(w1,   0,0,1088, 1088,1, 1088,1088, w1p, w1p+1152*1088);
  k_pack_w<<<dim3(5,1152),256,0,stream>>>(w2,   0,0,1088, 1088,1, 1088,1088, w2p, w2p+1152*1088);
  k_pack_w<<<dim3(5,1152),256,0,stream>>>(w_ag, 0,0,1088, 1088,1, 1088,1088, wagp, wagp+1152*1088);
  k_pack_w<<<dim3(5,1152),256,0,stream>>>(w_att,0,0,1088, 1088,1, 1088,1088, watp, watp+1152*1088);
  k_pack_w<<<dim3(5, 640),256,0,stream>>>(w_ag_s,0,0, 544, 1088,1,  544,1088, wagsp, wagsp+640*1088);
  // W^T stacked: B[o,k]=W0[k,o] (o<544) / W1[k,o-544]
  k_pack_w<<<dim3(3,1152),256,0,stream>>>(Wm, 0,544*544,544, 1,544, 1088,544, wWp, wWp+1152*544);
  k_q<<<4096,256,0,stream>>>(pos2d, w_pos, qb);

  // ---- GEMM chain ----
  // uv = f @ [Wl;Wr]^T  (f32 out)
  k_gemm<0><<<dim3(32,18),256,0,stream>>>(fhi,flo, wuv,wuv+2304*544, 544, 2176, 2176,
      uvb, nullptr,nullptr, nullptr,nullptr, nullptr,nullptr, nullptr, nullptr,nullptr);
  // h0 = relu(bnE(u_i+v_j)) + q_i - q_j + b_pos
  k_expand<<<1024,256,0,stream>>>(uvb, qb, bnbuf, b_pos, h0h, h0l);
  // r1 = relu(bn1(h0 @ w1^T))
  k_gemm<1><<<dim3(128,9),256,0,stream>>>(h0h,h0l, w1p,w1p+1152*1088, 1088, 1088, 1088,
      nullptr, r1h,r1l, bnbuf+2176, bnbuf+2176+1088, nullptr,nullptr, nullptr, nullptr,nullptr);
  // h2 = h0 + relu(bn2(r1 @ w2^T))
  k_gemm<2><<<dim3(128,9),256,0,stream>>>(r1h,r1l, w2p,w2p+1152*1088, 1088, 1088, 1088,
      nullptr, h2h,h2l, bnbuf+2*2176, bnbuf+2*2176+1088, h0h,h0l, nullptr, nullptr,nullptr);
  // a1 = relu(bnA(h2 @ w_ag^T))   (overwrites h0 region)
  k_gemm<1><<<dim3(128,9),256,0,stream>>>(h2h,h2l, wagp,wagp+1152*1088, 1088, 1088, 1088,
      nullptr, a1h,a1l, bnbuf+3*2176, bnbuf+3*2176+1088, nullptr,nullptr, nullptr, nullptr,nullptr);
  // ag = a1 @ w_ag_s^T + b_ag_s   (f32, overwrites r1 region)
  k_gemm<3><<<dim3(128,5),256,0,stream>>>(a1h,a1l, wagsp,wagsp+640*1088, 1088, 544, 544,
      agb, nullptr,nullptr, nullptr,nullptr, nullptr,nullptr, b_ag_s, nullptr,nullptr);
  // logits[m] = sum_o relu(bnT(h2 @ w_att^T))[m,o] * w_att_s[o]
  k_gemm<4><<<dim3(128,9),256,0,stream>>>(h2h,h2l, watp,watp+1152*1088, 1088, 1088, 1088,
      nullptr, nullptr,nullptr, bnbuf+4*2176, bnbuf+4*2176+1088, nullptr,nullptr, nullptr,
      w_att_s, logits);
  // fsft = f @ [W0 W1]  (f32)
  k_gemm<0><<<dim3(32,9),256,0,stream>>>(fhi,flo, wWp,wWp+1152*544, 544, 1088, 1088,
      fsft, nullptr,nullptr, nullptr,nullptr, nullptr,nullptr, nullptr, nullptr,nullptr);
  // final fuse + output layout
  k_fuse<<<1024,256,0,stream>>>(logits, agb, fsft, fmat, out);
}

// Round 4
// 935.660 us; speedup vs baseline: 1.0730x; 1.0730x over previous
//
#include <hip/hip_runtime.h>

typedef unsigned short u16;
typedef unsigned int   u32;
typedef __attribute__((ext_vector_type(4))) float f32x4;
typedef __attribute__((ext_vector_type(8))) short short8;

#define DI static __device__ __forceinline__

// ---- bf16 split helpers (round-to-nearest-even) ----
DI u16 f2bf(float x){ union{float f;u32 u;}v; v.f=x; u32 r=v.u + 0x7fffu + ((v.u>>16)&1u); return (u16)(r>>16); }
DI float bf2f(u16 h){ union{u32 u;float f;}v; v.u=((u32)h)<<16; return v.f; }

DI void gl_lds16(const u16* g, u16* l){
  __builtin_amdgcn_global_load_lds((const __attribute__((address_space(1))) void*)g,
                                   (__attribute__((address_space(3))) void*)l, 16, 0, 0);
}

// ===================== prep kernels =====================

__global__ void k_bnprep(const float* __restrict__ bnE, const float* __restrict__ bn1,
                         const float* __restrict__ bn2, const float* __restrict__ bnA,
                         const float* __restrict__ bnT, float* __restrict__ out){
  int i = blockIdx.x*256 + threadIdx.x;
  if(i >= 5*1088) return;
  int w = i/1088, c = i - w*1088;
  const float* b = (w==0)?bnE:(w==1)?bn1:(w==2)?bn2:(w==3)?bnA:bnT;
  float g=b[c], be=b[1088+c], mu=b[2176+c], va=b[3264+c];
  float s = g / sqrtf(va + 1e-5f);
  out[w*2176 + c] = s;
  out[w*2176 + 1088 + c] = be - mu*s;
}

__global__ void k_zero(float* p, int n){ int i = blockIdx.x*256+threadIdx.x; if(i<n) p[i]=0.f; }

__global__ void k_pack_f(const float* __restrict__ x, float* __restrict__ fmat,
                         u16* __restrict__ fhi, u16* __restrict__ flo){
  int bt = blockIdx.x;
  const float* xr = x + (size_t)bt*2176;
  for(int t=threadIdx.x; t<2176; t+=256){
    int c = t>>2, n = t&3;
    float v = xr[t];
    size_t o = (size_t)(bt*4+n)*544 + c;
    fmat[o] = v;
    u16 h = f2bf(v); fhi[o]=h; flo[o]=f2bf(v - bf2f(h));
  }
}

__global__ void k_pack_w(const float* __restrict__ src, int off1, int off2, int O1,
                         int rs, int cs, int O, int K,
                         u16* __restrict__ dhi, u16* __restrict__ dlo){
  int o = blockIdx.y;
  int k = blockIdx.x*256 + threadIdx.x;
  if(k >= K) return;
  float v = 0.f;
  if(o < O){
    size_t idx = (o<O1) ? (size_t)off1 + (size_t)o*rs + (size_t)k*cs
                        : (size_t)off2 + (size_t)(o-O1)*rs + (size_t)k*cs;
    v = src[idx];
  }
  size_t d = (size_t)o*K + k;
  u16 h=f2bf(v); dhi[d]=h; dlo[d]=f2bf(v - bf2f(h));
}

__global__ void k_q(const float* __restrict__ pos, const float* __restrict__ w_pos,
                    float* __restrict__ q){
  int m = blockIdx.x; int bt = m>>2, n = m&3;
  __shared__ float pr[34];
  if(threadIdx.x<34){ int j = threadIdx.x>>1, d = threadIdx.x&1;
    pr[threadIdx.x] = pos[(size_t)bt*136 + j*8 + d*4 + n]; }
  __syncthreads();
  for(int o=threadIdx.x;o<1088;o+=256){
    const float* wr = w_pos + (size_t)o*34;
    float s = 0.f;
    #pragma unroll
    for(int k=0;k<34;k++) s += pr[k]*wr[k];
    q[(size_t)m*1088 + o] = s;
  }
}

__global__ void k_expand(const float* __restrict__ uv, const float* __restrict__ q,
                         const float* __restrict__ bn, const float* __restrict__ b_pos,
                         u16* __restrict__ hh, u16* __restrict__ hl){
  __shared__ float su[4][1088], sv[4][1088], sq[4][1088];
  int bt = blockIdx.x;
  for(int t=threadIdx.x; t<4*1088; t+=256){
    int r = t/1088, o = t - r*1088;
    su[r][o] = uv[(size_t)(bt*4+r)*2176 + o];
    sv[r][o] = uv[(size_t)(bt*4+r)*2176 + 1088 + o];
    sq[r][o] = q[(size_t)(bt*4+r)*1088 + o];
  }
  __syncthreads();
  for(int t=threadIdx.x; t<16*1088; t+=256){
    int ij = t/1088, o = t - ij*1088; int i = ij>>2, j = ij&3;
    float xv = bn[o]*(su[i][o]+sv[j][o]) + bn[1088+o];
    xv = fmaxf(xv,0.f) + sq[i][o]-sq[j][o]+b_pos[o];
    size_t idx = (size_t)(bt*16+ij)*1088 + o;
    u16 h=f2bf(xv); hh[idx]=h; hl[idx]=f2bf(xv-bf2f(h));
  }
}

// ===================== split-bf16 MFMA GEMM =====================
// 128x128 tile, BK=32, 4 waves (2x2) of 64x64, mfma 16x16x32_bf16 x3 (hh, lh, hl).
// Counted-vmcnt pipeline (T4): stage(t+2) issued each iter; waits are vmcnt(8),
// never 0, so prefetch loads stay in flight across both barriers.
// Race-freedom: tile k+1's 8 loads are the oldest 8 of 16 outstanding at the
// end-of-iter vmcnt(8); the following s_barrier makes every wave's slice
// visible. Writes into a buffer occur only after the barrier that follows all
// waves' reads of it. Tail iters re-stage tile NT-1 into the dead buffer
// (harmless; keeps vm counts wave-uniform).
// XCD remap: same-A-panel blocks contiguous on one XCD (grid elems % 8 == 0).
// EPI: 0=f32 store 1=bn+relu split 2=bn+relu+residual split 3=+bias f32
//      4=bn+relu*wred[col] row-reduce -> atomicAdd
template<int EPI>
__global__ __launch_bounds__(256,2)
void k_gemm(const u16* __restrict__ Ahi, const u16* __restrict__ Alo,
            const u16* __restrict__ Bhi, const u16* __restrict__ Blo,
            int K, int Nout, int ldo,
            float* __restrict__ out_f, u16* __restrict__ out_hi, u16* __restrict__ out_lo,
            const float* __restrict__ sv, const float* __restrict__ tv,
            const u16* __restrict__ res_hi, const u16* __restrict__ res_lo,
            const float* __restrict__ bias,
            const float* __restrict__ wred, float* __restrict__ red_out)
{
  __shared__ u16 Ah[2][4096], Al[2][4096], Bh[2][4096], Bl[2][4096];
  __shared__ float red[128];
  const int tid = threadIdx.x, lane = tid&63, wave = tid>>6;
  const int wm = wave>>1, wn = wave&1;

  const int gx = gridDim.x, gy = gridDim.y;
  const int flat = blockIdx.y*gx + blockIdx.x;
  const int chunk = (gx*gy) >> 3;
  const int p = (flat & 7)*chunk + (flat >> 3);
  const int bx = p/gy, by = p - bx*gy;
  const int m0 = bx*128, n0 = by*128;
  if(EPI==4 && tid<128) red[tid]=0.f;

  auto stage = [&](int buf, int kt){
    const int k0 = kt*32;
    #pragma unroll
    for(int c=0;c<2;c++){
      int s   = (wave*2+c)*64 + lane;      // 16B slot index 0..511
      int row = s>>2;
      int kg  = (s&3) ^ ((row>>1)&3);      // inverse swizzle on global side
      size_t ga = (size_t)(m0+row)*K + k0 + kg*8;
      size_t gb = (size_t)(n0+row)*K + k0 + kg*8;
      int lo = (wave*2+c)*512;             // u16 offset (wave-uniform)
      gl_lds16(Ahi+ga, &Ah[buf][lo]);
      gl_lds16(Alo+ga, &Al[buf][lo]);
      gl_lds16(Bhi+gb, &Bh[buf][lo]);
      gl_lds16(Blo+gb, &Bl[buf][lo]);
    }
  };

  f32x4 acc[4][4];
  #pragma unroll
  for(int i=0;i<4;i++)
    #pragma unroll
    for(int j=0;j<4;j++){ acc[i][j][0]=0.f; acc[i][j][1]=0.f; acc[i][j][2]=0.f; acc[i][j][3]=0.f; }

  const int NT = K>>5;
  stage(0,0);
  stage(1,1);                               // 16 loads outstanding
  asm volatile("s_waitcnt vmcnt(8)" ::: "memory");   // stage(0) retired
  __builtin_amdgcn_sched_barrier(0);
  __builtin_amdgcn_s_barrier();

  const int swz = ((lane>>4) ^ (((lane&15)>>1)&3))<<3;
  const int iA = ((wm*64 + (lane&15))<<5) + swz;
  const int iB = ((wn*64 + (lane&15))<<5) + swz;

  for(int kt=0; kt<NT; ++kt){
    const int buf = kt&1;
    short8 ah[4],al[4],bh[4],bl[4];
    #pragma unroll
    for(int i=0;i<4;i++){
      ah[i] = *(const short8*)&Ah[buf][iA + i*512];
      al[i] = *(const short8*)&Al[buf][iA + i*512];
      bh[i] = *(const short8*)&Bh[buf][iB + i*512];
      bl[i] = *(const short8*)&Bl[buf][iB + i*512];
    }
    asm volatile("s_waitcnt lgkmcnt(0)" ::: "memory");
    __builtin_amdgcn_sched_barrier(0);
    __builtin_amdgcn_s_barrier();           // all waves done reading buf
    int kt2 = kt+2; if(kt2 > NT-1) kt2 = NT-1;
    stage(buf, kt2);
    __builtin_amdgcn_s_setprio(1);
    #pragma unroll
    for(int mi=0;mi<4;mi++)
      #pragma unroll
      for(int ni=0;ni<4;ni++)
        acc[mi][ni] = __builtin_amdgcn_mfma_f32_16x16x32_bf16(ah[mi],bh[ni],acc[mi][ni],0,0,0);
    #pragma unroll
    for(int mi=0;mi<4;mi++)
      #pragma unroll
      for(int ni=0;ni<4;ni++)
        acc[mi][ni] = __builtin_amdgcn_mfma_f32_16x16x32_bf16(al[mi],bh[ni],acc[mi][ni],0,0,0);
    #pragma unroll
    for(int mi=0;mi<4;mi++)
      #pragma unroll
      for(int ni=0;ni<4;ni++)
        acc[mi][ni] = __builtin_amdgcn_mfma_f32_16x16x32_bf16(ah[mi],bl[ni],acc[mi][ni],0,0,0);
    __builtin_amdgcn_s_setprio(0);
    asm volatile("s_waitcnt vmcnt(8)" ::: "memory");
    __builtin_amdgcn_sched_barrier(0);
    __builtin_amdgcn_s_barrier();
  }

  const int r0 = m0 + wm*64 + ((lane>>4)<<2);
  const int c0 = n0 + wn*64 + (lane&15);

  if constexpr (EPI==0){
    #pragma unroll
    for(int mi=0;mi<4;mi++)
      #pragma unroll
      for(int ni=0;ni<4;ni++){
        int col = c0 + ni*16;
        if(col < Nout){
          #pragma unroll
          for(int r=0;r<4;r++)
            out_f[(size_t)(r0+mi*16+r)*ldo + col] = acc[mi][ni][r];
        }
      }
  } else if constexpr (EPI==1 || EPI==2){
    #pragma unroll
    for(int mi=0;mi<4;mi++)
      #pragma unroll
      for(int ni=0;ni<4;ni++){
        int col = c0 + ni*16;
        if(col < Nout){
          float sc = sv[col], tc = tv[col];
          #pragma unroll
          for(int r=0;r<4;r++){
            float y = fmaxf(acc[mi][ni][r]*sc + tc, 0.f);
            size_t idx = (size_t)(r0+mi*16+r)*ldo + col;
            if(EPI==2) y += bf2f(res_hi[idx]) + bf2f(res_lo[idx]);
            u16 h = f2bf(y); out_hi[idx]=h; out_lo[idx]=f2bf(y - bf2f(h));
          }
        }
      }
  } else if constexpr (EPI==3){
    #pragma unroll
    for(int mi=0;mi<4;mi++)
      #pragma unroll
      for(int ni=0;ni<4;ni++){
        int col = c0 + ni*16;
        if(col < Nout){
          float bc = bias[col];
          #pragma unroll
          for(int r=0;r<4;r++)
            out_f[(size_t)(r0+mi*16+r)*ldo + col] = acc[mi][ni][r] + bc;
        }
      }
  } else { // EPI==4
    float rs4[4][4];
    #pragma unroll
    for(int mi=0;mi<4;mi++)
      #pragma unroll
      for(int r=0;r<4;r++) rs4[mi][r]=0.f;
    #pragma unroll
    for(int mi=0;mi<4;mi++)
      #pragma unroll
      for(int ni=0;ni<4;ni++){
        int col = c0 + ni*16;
        if(col < Nout){
          float sc = sv[col], tc = tv[col], wc = wred[col];
          #pragma unroll
          for(int r=0;r<4;r++)
            rs4[mi][r] += fmaxf(acc[mi][ni][r]*sc + tc, 0.f)*wc;
        }
      }
    #pragma unroll
    for(int off=1; off<16; off<<=1)
      #pragma unroll
      for(int mi=0;mi<4;mi++)
        #pragma unroll
        for(int r=0;r<4;r++)
          rs4[mi][r] += __shfl_xor(rs4[mi][r], off, 64);
    if((lane&15)==0){
      #pragma unroll
      for(int mi=0;mi<4;mi++)
        #pragma unroll
        for(int r=0;r<4;r++)
          atomicAdd(&red[wm*64 + mi*16 + ((lane>>4)<<2) + r], rs4[mi][r]);
    }
    __syncthreads();
    if(tid<128) atomicAdd(&red_out[m0+tid], red[tid]);
  }
}

// ===================== final fuse =====================
__global__ void k_fuse(const float* __restrict__ logits, const float* __restrict__ ag,
                       const float* __restrict__ fsft, const float* __restrict__ fmat,
                       float* __restrict__ out){
  int bt = blockIdx.x;
  float a[4][4];
  #pragma unroll
  for(int i=0;i<4;i++){
    float l0=logits[bt*16+i*4+0], l1=logits[bt*16+i*4+1],
          l2=logits[bt*16+i*4+2], l3=logits[bt*16+i*4+3];
    float mx = fmaxf(fmaxf(l0,l1),fmaxf(l2,l3));
    float e0=__expf(l0-mx), e1=__expf(l1-mx), e2=__expf(l2-mx), e3=__expf(l3-mx);
    float inv = 1.f/(e0+e1+e2+e3);
    a[i][0]=e0*inv; a[i][1]=e1*inv; a[i][2]=e2*inv; a[i][3]=e3*inv;
  }
  for(int d=threadIdx.x; d<544; d+=256){
    float fsv[4], ftv[4], fv[4];
    #pragma unroll
    for(int j=0;j<4;j++){
      fsv[j] = fsft[(size_t)(bt*4+j)*1088 + d];
      ftv[j] = fsft[(size_t)(bt*4+j)*1088 + 544 + d];
      fv[j]  = fmat[(size_t)(bt*4+j)*544 + d];
    }
    float o4[4];
    #pragma unroll
    for(int i=0;i<4;i++){
      float s = fv[i];
      #pragma unroll
      for(int j=0;j<4;j++){
        float fc = (j==i) ? fsv[j] : ftv[j]*ag[(size_t)(bt*16+i*4+j)*544 + d];
        s += a[i][j]*fc;
      }
      o4[i]=s;
    }
    *(float4*)(out + ((size_t)bt*544 + d)*4) = make_float4(o4[0],o4[1],o4[2],o4[3]);
  }
}

// ===================== launch =====================
extern "C" void kernel_launch(void* const* d_in, const int* in_sizes, int n_in,
                              void* d_out, int out_size, void* d_ws, size_t ws_size,
                              hipStream_t stream){
  (void)in_sizes; (void)n_in; (void)out_size; (void)ws_size;
  const float* x      = (const float*)d_in[0];
  const float* pos2d  = (const float*)d_in[1];
  const float* w_pos  = (const float*)d_in[2];
  const float* b_pos  = (const float*)d_in[3];
  const float* w_exp  = (const float*)d_in[4];
  const float* bnE    = (const float*)d_in[5];
  const float* w1     = (const float*)d_in[6];
  const float* bn1    = (const float*)d_in[7];
  const float* w2     = (const float*)d_in[8];
  const float* bn2    = (const float*)d_in[9];
  const float* w_ag   = (const float*)d_in[10];
  const float* bnA    = (const float*)d_in[11];
  const float* w_ag_s = (const float*)d_in[12];
  const float* b_ag_s = (const float*)d_in[13];
  const float* w_att  = (const float*)d_in[14];
  const float* bnT    = (const float*)d_in[15];
  const float* w_att_s= (const float*)d_in[16];
  // d_in[17] = b_att_s: scalar shift of softmax logits -> exactly cancels; unused.
  const float* Wm     = (const float*)d_in[18];
  float* out = (float*)d_out;

  char* ws = (char*)d_ws;
  size_t off = 0;
  auto alloc = [&](size_t b)->char*{ char* p = ws+off; off += (b+255)&~(size_t)255; return p; };

  float* fmat  = (float*)alloc(8912896);           // [4096,544] f32
  u16*   fhi   = (u16*)  alloc(4456448);
  u16*   flo   = (u16*)  alloc(4456448);
  float* bnbuf = (float*)alloc(43520);             // 5 x (scale[1088], shift[1088])
  u16*   wuv   = (u16*)  alloc(5013504);           // [2304,544] hi, lo at +2304*544
  u16*   w1p   = (u16*)  alloc(5013504);           // [1152,1088]
  u16*   w2p   = (u16*)  alloc(5013504);
  u16*   wagp  = (u16*)  alloc(5013504);
  u16*   watp  = (u16*)  alloc(5013504);
  u16*   wagsp = (u16*)  alloc(2785280);           // [640,1088]
  u16*   wWp   = (u16*)  alloc(2506752);           // [1152,544]
  float* logits= (float*)alloc(65536);             // [16384]
  char*  X0    = alloc(71303168);                  // h0 -> a1
  char*  X1    = alloc(71303168);                  // q -> r1 -> (ag | fsft)
  char*  X2    = alloc(71303168);                  // uv -> h2

  u16* h0h=(u16*)X0;            u16* h0l=(u16*)(X0+35651584);
  u16* a1h=(u16*)X0;            u16* a1l=(u16*)(X0+35651584);
  float* qb =(float*)X1;
  u16* r1h=(u16*)X1;            u16* r1l=(u16*)(X1+35651584);
  float* agb =(float*)X1;       float* fsft=(float*)(X1+35651584);
  float* uvb =(float*)X2;
  u16* h2h=(u16*)X2;            u16* h2l=(u16*)(X2+35651584);

  // ---- prep ----
  k_bnprep<<<22,256,0,stream>>>(bnE,bn1,bn2,bnA,bnT,bnbuf);
  k_zero  <<<64,256,0,stream>>>(logits,16384);
  k_pack_f<<<1024,256,0,stream>>>(x, fmat, fhi, flo);
  k_pack_w<<<dim3(3,2304),256,0,stream>>>(w_exp, 0,544,1088, 1088,1, 2176,544, wuv, wuv+2304*544);
  k_pack_w<<<dim3(5,1152),256,0,stream>>>(w1,   0,0,1088, 1088,1, 1088,1088, w1p, w1p+1152*1088);
  k_pack_w<<<dim3(5,1152),256,0,stream>>>(w2,   0,0,1088, 1088,1, 1088,1088, w2p, w2p+1152*1088);
  k_pack_w<<<dim3(5,1152),256,0,stream>>>(w_ag, 0,0,1088, 1088,1, 1088,1088, wagp, wagp+1152*1088);
  k_pack_w<<<dim3(5,1152),256,0,stream>>>(w_att,0,0,1088, 1088,1, 1088,1088, watp, watp+1152*1088);
  k_pack_w<<<dim3(5, 640),256,0,stream>>>(w_ag_s,0,0, 544, 1088,1,  544,1088, wagsp, wagsp+640*1088);
  k_pack_w<<<dim3(3,1152),256,0,stream>>>(Wm, 0,544*544,544, 1,544, 1088,544, wWp, wWp+1152*544);
  k_q<<<4096,256,0,stream>>>(pos2d, w_pos, qb);

  // ---- GEMM chain ----
  k_gemm<0><<<dim3(32,18),256,0,stream>>>(fhi,flo, wuv,wuv+2304*544, 544, 2176, 2176,
      uvb, nullptr,nullptr, nullptr,nullptr, nullptr,nullptr, nullptr, nullptr,nullptr);
  k_expand<<<1024,256,0,stream>>>(uvb, qb, bnbuf, b_pos, h0h, h0l);
  k_gemm<1><<<dim3(128,9),256,0,stream>>>(h0h,h0l, w1p,w1p+1152*1088, 1088, 1088, 1088,
      nullptr, r1h,r1l, bnbuf+2176, bnbuf+2176+1088, nullptr,nullptr, nullptr, nullptr,nullptr);
  k_gemm<2><<<dim3(128,9),256,0,stream>>>(r1h,r1l, w2p,w2p+1152*1088, 1088, 1088, 1088,
      nullptr, h2h,h2l, bnbuf+2*2176, bnbuf+2*2176+1088, h0h,h0l, nullptr, nullptr,nullptr);
  k_gemm<1><<<dim3(128,9),256,0,stream>>>(h2h,h2l, wagp,wagp+1152*1088, 1088, 1088, 1088,
      nullptr, a1h,a1l, bnbuf+3*2176, bnbuf+3*2176+1088, nullptr,nullptr, nullptr, nullptr,nullptr);
  k_gemm<3><<<dim3(128,5),256,0,stream>>>(a1h,a1l, wagsp,wagsp+640*1088, 1088, 544, 544,
      agb, nullptr,nullptr, nullptr,nullptr, nullptr,nullptr, b_ag_s, nullptr,nullptr);
  k_gemm<4><<<dim3(128,9),256,0,stream>>>(h2h,h2l, watp,watp+1152*1088, 1088, 1088, 1088,
      nullptr, nullptr,nullptr, bnbuf+4*2176, bnbuf+4*2176+1088, nullptr,nullptr, nullptr,
      w_att_s, logits);
  k_gemm<0><<<dim3(32,9),256,0,stream>>>(fhi,flo, wWp,wWp+1152*544, 544, 1088, 1088,
      fsft, nullptr,nullptr, nullptr,nullptr, nullptr,nullptr, nullptr, nullptr,nullptr);
  k_fuse<<<1024,256,0,stream>>>(logits, agb, fsft, fmat, out);
}